// Round 7
// baseline (230.981 us; speedup 1.0000x reference)
//
#include <hip/hip_runtime.h>
#include <hip/hip_bf16.h>

typedef __attribute__((ext_vector_type(8))) short bf16x8;   // 8 bf16 = 4 VGPRs
typedef __attribute__((ext_vector_type(4))) float f32x4;    // MFMA C/D frag

#define Qn 4096
#define Mn 8192
#define Dn 128
#define NWA 8                    // waves per block (512 threads)
#define QB 128                   // q-rows per block (16 per wave)
#define MSPLIT 16                // M split across block groups (2 slices/XCD)
#define BCOLS (Mn / MSPLIT)      // 512 cols per block
#define TILE 64                  // m-cols per staged tile
#define NIT (BCOLS / TILE)       // 8 iterations per block

__device__ __forceinline__ unsigned short f2bf(float x) {
  __hip_bfloat16 h = __float2bfloat16(x);
  return *reinterpret_cast<unsigned short*>(&h);
}

// Async global->LDS, 16B per lane. LDS dest is WAVE-UNIFORM base (HW adds
// lane*16); global src is per-lane.
__device__ __forceinline__ void gld_lds16(const void* g, void* l) {
  __builtin_amdgcn_global_load_lds(
      (const __attribute__((address_space(1))) unsigned int*)g,
      (__attribute__((address_space(3))) unsigned int*)l, 16, 0, 0);
}

__global__ void zero_kernel(float4* __restrict__ p, int n4) {
  int i = blockIdx.x * blockDim.x + threadIdx.x;
  if (i < n4) p[i] = make_float4(0.f, 0.f, 0.f, 0.f);
}

// Q * (1/sqrt(D)) -> bf16, vectorized
__global__ void cast_q(const float4* __restrict__ Q4, ushort4* __restrict__ Qs) {
  int i = blockIdx.x * blockDim.x + threadIdx.x;   // < Qn*Dn/4
  const float s = 0.088388347648318447f;           // 1/sqrt(128)
  float4 q = Q4[i];
  Qs[i] = make_ushort4(f2bf(q.x * s), f2bf(q.y * s), f2bf(q.z * s), f2bf(q.w * s));
}

// Swizzle K into MFMA-fragment-major bf16 layouts (proven R5). Key property:
// a 64-col tile at 64-aligned m0 is a CONTIGUOUS 16KB region at byte offset
// m0*256 in both arrays -> staged into LDS linearly; fragment reads use the
// same in-tile offsets:
//  Kswz in-tile frag: ((a*4+kk)*64 + lane)*8 shorts  (a = m-subtile 0..3)
//  Vswz in-tile frag: ((n*2+kk)*64 + lane)*8 shorts  (n = d-subtile 0..7)
__global__ __launch_bounds__(256) void swz_kernel(const float* __restrict__ K,
                                                  unsigned short* __restrict__ Kswz,
                                                  unsigned short* __restrict__ Vswz) {
  __shared__ __align__(16) unsigned short T[64][72];   // 64m x 64d tile, bf16, padded
  const int m0 = blockIdx.x * 64, d0 = blockIdx.y * 64;
  const int t = threadIdx.x;
  const int r = t >> 4, c4 = (t & 15) * 4;
#pragma unroll
  for (int rr = 0; rr < 64; rr += 16) {
    float4 v = *reinterpret_cast<const float4*>(&K[(size_t)(m0 + r + rr) * Dn + d0 + c4]);
    ushort4 b = make_ushort4(f2bf(v.x), f2bf(v.y), f2bf(v.z), f2bf(v.w));
    *reinterpret_cast<ushort4*>(&T[r + rr][c4]) = b;
  }
  __syncthreads();
#pragma unroll
  for (int rep = 0; rep < 2; ++rep) {
    int w = t + rep * 256;
    int ml = w >> 3, oct = w & 7;
    uint4 val = *reinterpret_cast<uint4*>(&T[ml][oct * 8]);
    int m = m0 + ml, d = d0 + oct * 8;
    int g = m >> 4, l = m & 15, kk = d >> 5, quad = (d >> 3) & 3;
    *reinterpret_cast<uint4*>(&Kswz[(size_t)(((g * 4 + kk) * 64) + quad * 16 + l) * 8]) = val;
  }
#pragma unroll
  for (int rep = 0; rep < 2; ++rep) {
    int w = t + rep * 256;
    int dl = w >> 3, moct = w & 7;
    unsigned short tmp[8];
#pragma unroll
    for (int j = 0; j < 8; ++j) tmp[j] = T[moct * 8 + j][dl];
    int d = d0 + dl, m = m0 + moct * 8;
    int np = d >> 4, lB = d & 15, mt = m >> 6, mm = m & 63, kk2 = mm >> 5, qB = (mm >> 3) & 3;
    *reinterpret_cast<uint4*>(
        &Vswz[(size_t)((((mt * 8 + np) * 2 + kk2) * 64) + qB * 16 + lB) * 8]) =
        *reinterpret_cast<uint4*>(tmp);
  }
}

// R7: MSPLIT 16 -> grid 512 = 2 blocks/CU. R6 (grid 256, 1 block/CU,
// single-buffered LDS + full-drain barriers) exposed ~100K cy of stage
// latency: nothing else resident to run during the vmcnt(0) drains. With a
// second block per CU, one block computes while the other drains (R5
// regime). Traffic ledger unchanged by MSPLIT (K/V staging scales only
// with Qn/QB): K/V 32.5K + W 33K + atomics 32K ~= 98K lane-cy/CU ~= 41us.
//
// waves_per_eu(4,4): 2 blocks x 8 waves = 4 waves/SIMD requires <=128-reg
// budget; allocator chose 88 under (2,2) so 128 is safe headroom (R3's
// (4,4) spill was a ~150-reg live set -- not this kernel). Tripwire:
// VGPR<88 or WRITE_SIZE>>20MB means spill -> revert.
//
// LDS = K 16KB + V 16KB + W 8x4KB = 64KB; 2 blocks = 128KB <= 160KB/CU.
// P (bf16 [16][72]) ALIASES the per-wave W region (union): W -> regs,
// lgkmcnt(0) fence, P overwrites; per-wave-private, in-order DS pipe.
// W LDS swizzle: store col' = col ^ ((row>>2)*16) via pre-XORed SOURCE col
// (gld_lds dest must stay linear); read with same XOR -> 2-way alias, free.
//
// XCD residency: blocks b and b+8 land on the same XCD (HW %8 round-robin);
// their two 512-col slices total 512KB K/V per XCD L2, same as R6.
__global__ __launch_bounds__(512) __attribute__((amdgpu_waves_per_eu(4, 4)))
void attn_kernel(const float* __restrict__ W,
                 const unsigned short* __restrict__ Qs,
                 const unsigned short* __restrict__ Kswz,
                 const unsigned short* __restrict__ Vswz,
                 float* __restrict__ Oacc,
                 float* __restrict__ Lacc) {
  __shared__ __align__(16) unsigned short Klds[16 * 64 * 8];   // 16KB K tile
  __shared__ __align__(16) unsigned short Vlds[16 * 64 * 8];   // 16KB V tile
  __shared__ __align__(16) unsigned char  WP[NWA][4096];       // 32KB W fp32 / P bf16 union

  const int tid  = threadIdx.x;
  const int wave = tid >> 6;
  const int lane = tid & 63;
  const int l    = lane & 15;
  const int quad = lane >> 4;
  const int b    = blockIdx.x;
  const int qb   = (b >> 4) * QB;      // 32 q-blocks
  const int mbeg = (b & 15) * BCOLS;   // m-slice (2 slices per XCD)
  const int qw   = qb + wave * 16;     // this wave's q-row base

  // Persistent Q A-fragments for this wave's 16 rows.
  bf16x8 aq[4];
  {
    const unsigned short* qrow = Qs + (size_t)(qw + l) * Dn + quad * 8;
#pragma unroll
    for (int kk = 0; kk < 4; ++kk)
      aq[kk] = *reinterpret_cast<const bf16x8*>(qrow + 32 * kk);
  }

  f32x4 O[8];
#pragma unroll
  for (int n = 0; n < 8; ++n) O[n] = (f32x4){0.f, 0.f, 0.f, 0.f};
  float lsum[4] = {0.f, 0.f, 0.f, 0.f};

  for (int it = 0; it < NIT; ++it) {
    const int m0 = mbeg + it * TILE;
    __syncthreads();   // prev tile's LDS reads done before overwrite

    // Stage K/V tiles: 16KB each = 16 chunks of 1KB; wave stages 2+2.
    {
      const unsigned short* ksrc = Kswz + (size_t)m0 * 128;
      const unsigned short* vsrc = Vswz + (size_t)m0 * 128;
#pragma unroll
      for (int i = 0; i < 2; ++i) {
        const int c = wave * 2 + i;
        gld_lds16(ksrc + (size_t)c * 512 + lane * 8, &Klds[c * 512]);
        gld_lds16(vsrc + (size_t)c * 512 + lane * 8, &Vlds[c * 512]);
      }
    }
    // Stage this wave's W tile: 16 rows x 64 cols fp32 (4KB = 4 chunks),
    // row-major with source-col XOR (i = row>>2 for the rows this chunk
    // covers). Lane: row i*4+(lane>>4), cols ((lane&15)*4)^(i*16) .. +3.
#pragma unroll
    for (int i = 0; i < 4; ++i) {
      const float* wsrc = &W[(size_t)(qw + i * 4 + (lane >> 4)) * Mn + m0 +
                             (((lane & 15) * 4) ^ (i * 16))];
      gld_lds16(wsrc, &WP[wave][i * 1024]);
    }
    __syncthreads();   // vmcnt(0) drain + barrier: tiles ready

    // QK^T: S[a] = Q(16q x 128) . K^T for m-subtile a (16 cols each).
    f32x4 S[4];
#pragma unroll
    for (int a = 0; a < 4; ++a) S[a] = (f32x4){0.f, 0.f, 0.f, 0.f};
#pragma unroll
    for (int a = 0; a < 4; ++a)
#pragma unroll
      for (int kk = 0; kk < 4; ++kk) {
        bf16x8 bk = *reinterpret_cast<const bf16x8*>(
            &Klds[((a * 4 + kk) * 64 + lane) * 8]);
        S[a] = __builtin_amdgcn_mfma_f32_16x16x32_bf16(aq[kk], bk, S[a], 0, 0, 0);
      }

    // W -> regs (2-way bank alias via XOR: free), then fence so P may
    // overwrite the W region.
    float wv[16];
#pragma unroll
    for (int a = 0; a < 4; ++a)
#pragma unroll
      for (int r = 0; r < 4; ++r)
        wv[a * 4 + r] = *reinterpret_cast<const float*>(
            &WP[wave][(size_t)(((quad * 4 + r) * 64) +
                               ((16 * a + l) ^ (quad * 16))) * 4]);
    asm volatile("s_waitcnt lgkmcnt(0)" ::: "memory");   // W landed; region reusable

    // P = exp(S*W) -> bf16 into the (now dead) W region, padded [16][72].
    unsigned short* P = reinterpret_cast<unsigned short*>(&WP[wave][0]);
#pragma unroll
    for (int a = 0; a < 4; ++a)
#pragma unroll
      for (int r = 0; r < 4; ++r) {
        float p = __expf(S[a][r] * wv[a * 4 + r]);
        lsum[r] += p;
        P[(quad * 4 + r) * 72 + 16 * a + l] = f2bf(p);
      }
    asm volatile("s_waitcnt lgkmcnt(0)" ::: "memory");   // P visible to own wave

    // PV: O += P(16q x 64m) . V(64m x 128d)
#pragma unroll
    for (int kk = 0; kk < 2; ++kk) {
      bf16x8 pa = *reinterpret_cast<const bf16x8*>(
          &P[l * 72 + 32 * kk + quad * 8]);
#pragma unroll
      for (int n = 0; n < 8; ++n) {
        bf16x8 bv = *reinterpret_cast<const bf16x8*>(
            &Vlds[((n * 2 + kk) * 64 + lane) * 8]);
        O[n] = __builtin_amdgcn_mfma_f32_16x16x32_bf16(pa, bv, O[n], 0, 0, 0);
      }
    }
  }

  // lsum reduce across the 16 l-lanes of each quad (m-cols live on l).
#pragma unroll
  for (int r = 0; r < 4; ++r)
#pragma unroll
    for (int off = 1; off < 16; off <<= 1)
      lsum[r] += __shfl_xor(lsum[r], off, 64);

  // Waves own distinct q-rows: no cross-wave combine. Cross-block (MSPLIT)
  // combine via device atomics.
#pragma unroll
  for (int n = 0; n < 8; ++n)
#pragma unroll
    for (int r = 0; r < 4; ++r)
      atomicAdd(&Oacc[(size_t)(qw + quad * 4 + r) * Dn + 16 * n + l], O[n][r]);
  if (l == 0)
#pragma unroll
    for (int r = 0; r < 4; ++r) atomicAdd(&Lacc[qw + quad * 4 + r], lsum[r]);
}

__global__ void finalize_kernel(const float4* __restrict__ Oacc,
                                const float* __restrict__ Lacc,
                                float4* __restrict__ out) {
  int i = blockIdx.x * blockDim.x + threadIdx.x;   // < Qn*Dn/4
  float4 o = Oacc[i];
  float inv = 1.0f / Lacc[i >> 5];                 // 32 float4 per row
  out[i] = make_float4(o.x * inv, o.y * inv, o.z * inv, o.w * inv);
}

extern "C" void kernel_launch(void* const* d_in, const int* in_sizes, int n_in,
                              void* d_out, int out_size, void* d_ws, size_t ws_size,
                              hipStream_t stream) {
  const float* Q = (const float*)d_in[0];          // [4096,128]
  const float* K = (const float*)d_in[1];          // [8192,128]
  const float* W = (const float*)d_in[2];          // [4096,8192]
  float* out = (float*)d_out;                      // [4096,128]

  unsigned short* Qs   = (unsigned short*)d_ws;               // 1 MB
  unsigned short* Kswz = Qs + (size_t)Qn * Dn;                // 2 MB
  unsigned short* Vswz = Kswz + (size_t)Mn * Dn;              // 2 MB
  float* Oacc = (float*)(Vswz + (size_t)Mn * Dn);             // 2 MB
  float* Lacc = Oacc + (size_t)Qn * Dn;                       // 16 KB (total 7.02 MB)

  int n4 = (Qn * Dn + Qn) / 4;                                // Oacc + Lacc zeroing
  zero_kernel<<<(n4 + 255) / 256, 256, 0, stream>>>((float4*)Oacc, n4);

  cast_q<<<(Qn * Dn / 4) / 256, 256, 0, stream>>>((const float4*)Q, (ushort4*)Qs);
  swz_kernel<<<dim3(Mn / 64, Dn / 64), 256, 0, stream>>>(K, Kswz, Vswz);
  attn_kernel<<<(Qn / QB) * MSPLIT, 512, 0, stream>>>(W, Qs, Kswz, Vswz, Oacc, Lacc);
  finalize_kernel<<<(Qn * Dn / 4) / 256, 256, 0, stream>>>(
      (const float4*)Oacc, Lacc, (float4*)out);
}

// Round 8
// 228.156 us; speedup vs baseline: 1.0124x; 1.0124x over previous
//
#include <hip/hip_runtime.h>
#include <hip/hip_bf16.h>

typedef __attribute__((ext_vector_type(8))) short bf16x8;   // 8 bf16 = 4 VGPRs
typedef __attribute__((ext_vector_type(4))) float f32x4;    // MFMA C/D frag

#define Qn 4096
#define Mn 8192
#define Dn 128
#define NWA 4                    // waves per block
#define QB 64                    // q-rows per block (16 per wave)
#define MSPLIT 8                 // M split across XCD-pinned block groups
#define BCOLS (Mn / MSPLIT)      // 1024 cols per block
#define TILE 64                  // m-cols per staged tile
#define NIT (BCOLS / TILE)       // 16 iterations per block (power of 2)

__device__ __forceinline__ unsigned short f2bf(float x) {
  __hip_bfloat16 h = __float2bfloat16(x);
  return *reinterpret_cast<unsigned short*>(&h);
}

// Async global->LDS, 16B per lane. LDS dest is WAVE-UNIFORM base (HW adds
// lane*16); global src is per-lane.
__device__ __forceinline__ void gld_lds16(const void* g, void* l) {
  __builtin_amdgcn_global_load_lds(
      (const __attribute__((address_space(1))) unsigned int*)g,
      (__attribute__((address_space(3))) unsigned int*)l, 16, 0, 0);
}

__global__ void zero_kernel(float4* __restrict__ p, int n4) {
  int i = blockIdx.x * blockDim.x + threadIdx.x;
  if (i < n4) p[i] = make_float4(0.f, 0.f, 0.f, 0.f);
}

// Q * (1/sqrt(D)) -> bf16, vectorized
__global__ void cast_q(const float4* __restrict__ Q4, ushort4* __restrict__ Qs) {
  int i = blockIdx.x * blockDim.x + threadIdx.x;   // < Qn*Dn/4
  const float s = 0.088388347648318447f;           // 1/sqrt(128)
  float4 q = Q4[i];
  Qs[i] = make_ushort4(f2bf(q.x * s), f2bf(q.y * s), f2bf(q.z * s), f2bf(q.w * s));
}

// Swizzle K into MFMA-fragment-major bf16 layouts (proven R5). Key property:
// a 64-col tile at 64-aligned m0 is a CONTIGUOUS 16KB region at byte offset
// m0*256 in both arrays -> staged into LDS linearly; fragment reads use the
// same in-tile offsets:
//  Kswz in-tile frag: ((a*4+kk)*64 + lane)*8 shorts  (a = m-subtile 0..3)
//  Vswz in-tile frag: ((n*2+kk)*64 + lane)*8 shorts  (n = d-subtile 0..7)
__global__ __launch_bounds__(256) void swz_kernel(const float* __restrict__ K,
                                                  unsigned short* __restrict__ Kswz,
                                                  unsigned short* __restrict__ Vswz) {
  __shared__ __align__(16) unsigned short T[64][72];   // 64m x 64d tile, bf16, padded
  const int m0 = blockIdx.x * 64, d0 = blockIdx.y * 64;
  const int t = threadIdx.x;
  const int r = t >> 4, c4 = (t & 15) * 4;
#pragma unroll
  for (int rr = 0; rr < 64; rr += 16) {
    float4 v = *reinterpret_cast<const float4*>(&K[(size_t)(m0 + r + rr) * Dn + d0 + c4]);
    ushort4 b = make_ushort4(f2bf(v.x), f2bf(v.y), f2bf(v.z), f2bf(v.w));
    *reinterpret_cast<ushort4*>(&T[r + rr][c4]) = b;
  }
  __syncthreads();
#pragma unroll
  for (int rep = 0; rep < 2; ++rep) {
    int w = t + rep * 256;
    int ml = w >> 3, oct = w & 7;
    uint4 val = *reinterpret_cast<uint4*>(&T[ml][oct * 8]);
    int m = m0 + ml, d = d0 + oct * 8;
    int g = m >> 4, l = m & 15, kk = d >> 5, quad = (d >> 3) & 3;
    *reinterpret_cast<uint4*>(&Kswz[(size_t)(((g * 4 + kk) * 64) + quad * 16 + l) * 8]) = val;
  }
#pragma unroll
  for (int rep = 0; rep < 2; ++rep) {
    int w = t + rep * 256;
    int dl = w >> 3, moct = w & 7;
    unsigned short tmp[8];
#pragma unroll
    for (int j = 0; j < 8; ++j) tmp[j] = T[moct * 8 + j][dl];
    int d = d0 + dl, m = m0 + moct * 8;
    int np = d >> 4, lB = d & 15, mt = m >> 6, mm = m & 63, kk2 = mm >> 5, qB = (mm >> 3) & 3;
    *reinterpret_cast<uint4*>(
        &Vswz[(size_t)((((mt * 8 + np) * 2 + kk2) * 64) + qB * 16 + lB) * 8]) =
        *reinterpret_cast<uint4*>(tmp);
  }
}

// R8 = R5 structure (best measured, ~60-65us attn) + W double-buffer with
// counted vmcnt. History: R6/R7 proved the QB=128/8-wave/W-union structure
// costs ~15us regardless of blocks/CU (78us at both 1 and 2 blocks/CU);
// R7's counters show near-ADDITIVE pipe usage (DS ~72K + VMEM ~65K + VALU
// 19K + MFMA 15K ~= 187K cy wall) -- barrier lockstep, no overlap. Revert
// to R5 (4-wave blocks, QB=64, MSPLIT=8, separate W/P LDS) and remove the
// one per-iter latency term R5 pays: the W stream's full vmcnt(0) drain.
//
// Pipeline: per iter, stage K/V(it) [8 gld_lds], then W(it+1) into the
// spare buffer [4 gld_lds], then s_waitcnt vmcnt(4) -- waits the 8 K/V
// (oldest), leaves the 4 W in flight -- then RAW s_barrier (no drain).
// W(it) was issued one full iteration ago; the loop-top __syncthreads'
// implicit vmcnt(0) drains it for free. W is wave-private (own gld_lds,
// own reads) so per-wave vmcnt ordering is sufficient for it; the barrier
// pair covers cross-wave K/V visibility.
//
// W LDS swizzle (proven R5): store col' = col ^ ((row>>2)*16) by pre-XORing
// the SOURCE col (gld_lds dest must stay linear); read with the same XOR ->
// 2-way bank alias (free).
//
// LDS = K 16KB + V 16KB + Wd 4x2x4KB = 32KB + P 9.2KB = 73.2KB -> 2
// blocks/CU (146.4 <= 160). waves_per_eu(2,2): 256-reg budget, no spill
// (R1/R3: pins >=4 waves/SIMD spill this family -- never again).
// XCD pin: all blocks on XCD x carry b&7==x -> one 512KB K/V slice per L2.
__global__ __launch_bounds__(256) __attribute__((amdgpu_waves_per_eu(2, 2)))
void attn_kernel(const float* __restrict__ W,
                 const unsigned short* __restrict__ Qs,
                 const unsigned short* __restrict__ Kswz,
                 const unsigned short* __restrict__ Vswz,
                 float* __restrict__ Oacc,
                 float* __restrict__ Lacc) {
  __shared__ __align__(16) unsigned short Klds[16 * 64 * 8];   // 16KB K tile
  __shared__ __align__(16) unsigned short Vlds[16 * 64 * 8];   // 16KB V tile
  __shared__ __align__(16) float Wd[NWA][2][16][64];           // 32KB W dbuf
  __shared__ __align__(16) unsigned short Plds[NWA][16][72];   // 9.2KB P

  const int tid  = threadIdx.x;
  const int wave = tid >> 6;
  const int lane = tid & 63;
  const int l    = lane & 15;
  const int quad = lane >> 4;
  const int b    = blockIdx.x;
  const int qb   = (b >> 3) * QB;      // 64 q-blocks
  const int mbeg = (b & 7) * BCOLS;    // XCD-pinned m-slice
  const int qw   = qb + wave * 16;     // this wave's q-row base

  // Persistent Q A-fragments for this wave's 16 rows.
  bf16x8 aq[4];
  {
    const unsigned short* qrow = Qs + (size_t)(qw + l) * Dn + quad * 8;
#pragma unroll
    for (int kk = 0; kk < 4; ++kk)
      aq[kk] = *reinterpret_cast<const bf16x8*>(qrow + 32 * kk);
  }

  f32x4 O[8];
#pragma unroll
  for (int n = 0; n < 8; ++n) O[n] = (f32x4){0.f, 0.f, 0.f, 0.f};
  float lsum[4] = {0.f, 0.f, 0.f, 0.f};

  // Stage this wave's W tile for a given m0 into Wd[wave][buf]:
  // 16 rows x 64 cols fp32 (4KB = 4 chunks), row-major with source-col XOR
  // (chunk i covers rows i*4..i*4+3; lane: row i*4+(lane>>4),
  //  cols ((lane&15)*4)^(i*16) .. +3 -- XOR preserves the float4).
#define STAGE_W(m0_, buf_)                                                       \
  {                                                                              \
    _Pragma("unroll") for (int i = 0; i < 4; ++i) {                              \
      const float* wsrc = &W[(size_t)(qw + i * 4 + (lane >> 4)) * Mn + (m0_) +   \
                             (((lane & 15) * 4) ^ (i * 16))];                    \
      gld_lds16(wsrc, &Wd[wave][buf_][i * 4][0]);                                \
    }                                                                            \
  }

  // Prologue: W(0) -> buf 0. Drained by iter 0's __syncthreads.
  STAGE_W(mbeg, 0);

  for (int it = 0; it < NIT; ++it) {
    const int m0 = mbeg + it * TILE;
    const int cur = it & 1;
    // (A) prev compute's LDS reads done before overwrite; implicit
    // vmcnt(0) also drains W(it) (in flight for a full iteration).
    __syncthreads();

    // Stage K/V tiles: 16KB each = 16 chunks of 1KB; wave stages 4+4.
    {
      const unsigned short* ksrc = Kswz + (size_t)m0 * 128;
      const unsigned short* vsrc = Vswz + (size_t)m0 * 128;
#pragma unroll
      for (int i = 0; i < 4; ++i) {
        const int c = wave * 4 + i;                 // 1KB chunk 0..15
        gld_lds16(ksrc + (size_t)c * 512 + lane * 8, &Klds[c * 512]);
        gld_lds16(vsrc + (size_t)c * 512 + lane * 8, &Vlds[c * 512]);
      }
    }
    // Prefetch W(it+1) into the spare buffer (wraps harmlessly at the end;
    // keeps the vmcnt arithmetic uniform: 4 newest outstanding are W).
    {
      const int itn = (it + 1) & (NIT - 1);
      STAGE_W(mbeg + itn * TILE, cur ^ 1);
    }
    // (B) Wait K/V only (8 oldest of 12); leave W(it+1) in flight. Raw
    // barrier: no vmcnt(0) drain. Cross-wave K/V visibility = each wave's
    // vmcnt(4) + barrier.
    asm volatile("s_waitcnt vmcnt(4)" ::: "memory");
    __builtin_amdgcn_s_barrier();

    // QK^T: S[a] = Q(16q x 128) . K^T for m-subtile a (16 cols each).
    f32x4 S[4];
#pragma unroll
    for (int a = 0; a < 4; ++a) S[a] = (f32x4){0.f, 0.f, 0.f, 0.f};
#pragma unroll
    for (int a = 0; a < 4; ++a)
#pragma unroll
      for (int kk = 0; kk < 4; ++kk) {
        bf16x8 bk = *reinterpret_cast<const bf16x8*>(
            &Klds[((a * 4 + kk) * 64 + lane) * 8]);
        S[a] = __builtin_amdgcn_mfma_f32_16x16x32_bf16(aq[kk], bk, S[a], 0, 0, 0);
      }

    // P = exp(S*W); W read straight from Wd[wave][cur] (2-way alias via
    // XOR: free). Stash bf16 P in LDS for the lane transpose.
#pragma unroll
    for (int a = 0; a < 4; ++a)
#pragma unroll
      for (int r = 0; r < 4; ++r) {
        float wv = Wd[wave][cur][quad * 4 + r][(16 * a + l) ^ (quad * 16)];
        float p = __expf(S[a][r] * wv);
        lsum[r] += p;
        Plds[wave][quad * 4 + r][16 * a + l] = f2bf(p);
      }
    asm volatile("s_waitcnt lgkmcnt(0)" ::: "memory");

    // PV: O += P(16q x 64m) . V(64m x 128d)
#pragma unroll
    for (int kk = 0; kk < 2; ++kk) {
      bf16x8 pa = *reinterpret_cast<const bf16x8*>(
          &Plds[wave][l][32 * kk + quad * 8]);
#pragma unroll
      for (int n = 0; n < 8; ++n) {
        bf16x8 bv = *reinterpret_cast<const bf16x8*>(
            &Vlds[((n * 2 + kk) * 64 + lane) * 8]);
        O[n] = __builtin_amdgcn_mfma_f32_16x16x32_bf16(pa, bv, O[n], 0, 0, 0);
      }
    }
  }
#undef STAGE_W

  // lsum reduce across the 16 l-lanes of each quad (m-cols live on l).
#pragma unroll
  for (int r = 0; r < 4; ++r)
#pragma unroll
    for (int off = 1; off < 16; off <<= 1)
      lsum[r] += __shfl_xor(lsum[r], off, 64);

  // Waves own distinct q-rows: no cross-wave combine. Cross-block (MSPLIT)
  // combine via device atomics.
#pragma unroll
  for (int n = 0; n < 8; ++n)
#pragma unroll
    for (int r = 0; r < 4; ++r)
      atomicAdd(&Oacc[(size_t)(qw + quad * 4 + r) * Dn + 16 * n + l], O[n][r]);
  if (l == 0)
#pragma unroll
    for (int r = 0; r < 4; ++r) atomicAdd(&Lacc[qw + quad * 4 + r], lsum[r]);
}

__global__ void finalize_kernel(const float4* __restrict__ Oacc,
                                const float* __restrict__ Lacc,
                                float4* __restrict__ out) {
  int i = blockIdx.x * blockDim.x + threadIdx.x;   // < Qn*Dn/4
  float4 o = Oacc[i];
  float inv = 1.0f / Lacc[i >> 5];                 // 32 float4 per row
  out[i] = make_float4(o.x * inv, o.y * inv, o.z * inv, o.w * inv);
}

extern "C" void kernel_launch(void* const* d_in, const int* in_sizes, int n_in,
                              void* d_out, int out_size, void* d_ws, size_t ws_size,
                              hipStream_t stream) {
  const float* Q = (const float*)d_in[0];          // [4096,128]
  const float* K = (const float*)d_in[1];          // [8192,128]
  const float* W = (const float*)d_in[2];          // [4096,8192]
  float* out = (float*)d_out;                      // [4096,128]

  unsigned short* Qs   = (unsigned short*)d_ws;               // 1 MB
  unsigned short* Kswz = Qs + (size_t)Qn * Dn;                // 2 MB
  unsigned short* Vswz = Kswz + (size_t)Mn * Dn;              // 2 MB
  float* Oacc = (float*)(Vswz + (size_t)Mn * Dn);             // 2 MB
  float* Lacc = Oacc + (size_t)Qn * Dn;                       // 16 KB (total 7.02 MB)

  int n4 = (Qn * Dn + Qn) / 4;                                // Oacc + Lacc zeroing
  zero_kernel<<<(n4 + 255) / 256, 256, 0, stream>>>((float4*)Oacc, n4);

  cast_q<<<(Qn * Dn / 4) / 256, 256, 0, stream>>>((const float4*)Q, (ushort4*)Qs);
  swz_kernel<<<dim3(Mn / 64, Dn / 64), 256, 0, stream>>>(K, Kswz, Vswz);
  attn_kernel<<<(Qn / QB) * MSPLIT, 256, 0, stream>>>(W, Qs, Kswz, Vswz, Oacc, Lacc);
  finalize_kernel<<<(Qn * Dn / 4) / 256, 256, 0, stream>>>(
      (const float4*)Oacc, Lacc, (float4*)out);
}